// Round 9
// baseline (526.681 us; speedup 1.0000x reference)
//
#include <hip/hip_runtime.h>

// Spiking self-attention block (spikformer SSA), MI355X fp32 implementation.
// T=4 B=32 C=384 H=W=14 (N=196), heads=8, d=48.
//
// Exactness: LIF spikes are EXACTLY 0/1; attention is exact integer math
// (order-independent). Conv GEMM: single fp32 accumulator per output,
// ascending K, fmaf per step (matched XLA bit-for-bit rounds 1-8). Any
// summation-order change risks LIF spike flips -> MFMA off the table.
//
// R9: (a) GEMM register-prefetch: tile c0+16 is loaded to VGPRs before
// computing tile c0 (R3 exposed full global latency between K-tiles:
// load -> ds_write(vmcnt0) -> barrier -> compute = the 27% stall).
// Same fmaf chain -> bit-exact. LDS stays 16 KB; VGPR ~100 (under the
// (256,2) 256-VGPR cap; the 64-VGPR trap was (256,4)/(768,3)).
// (b) k_mask reads n-contiguous float4 with bit-permuted masks
// (m -> word m&3, bit m>>2; popcounts over m invariant, qT re-indexed).
// (c) k_attn Phase-B split 4x via grid z (A2a/A2b recomputed per block).

#define T_ 4
#define B_ 32
#define C_ 384
#define N_ 196
#define NH_ 8
#define D_ 48
#define TB_ (T_ * B_)                 // 128
#define CN_ ((size_t)C_ * N_)         // 75264
#define BCN4_ (B_ * C_ * (N_ / 4))    // 602112 float4 units per (g,t)
#define TBCN_ ((size_t)T_ * B_ * C_ * N_)  // 9,633,792 floats
typedef unsigned long long u64;

// ---------------------------------------------------------------------------
// GEMM (R3 tiling + register prefetch): Y[g][tb][co][n] = sum_c W[co][c]*X[tb][c][n]
// Cols flattened j = tb*196 + n; 25088 = 196 tiles of 128 (exact).
// Block: 128co x 128col, 256 thr, 8x8/thread in two stride-64 quads.
// grid: x = col-tile (196), y = co-tile (3), z = g
// ---------------------------------------------------------------------------
__global__ __launch_bounds__(256, 2) void gemm_f32(
    const float* __restrict__ X, const float* __restrict__ W0,
    const float* __restrict__ W1, const float* __restrict__ W2,
    float* __restrict__ P)
{
  const int g = blockIdx.z;
  const float* __restrict__ W = (g == 0) ? W0 : (g == 1) ? W1 : W2;
  const int co0 = blockIdx.y * 128;
  const int j0 = blockIdx.x * 128;
  __shared__ float As[16][128];
  __shared__ float Bs[16][128];
  const int tid = threadIdx.x;
  const int tx = tid & 15, ty = tid >> 4;

  const int bcol = (tid & 31) * 4;
  const int bk = tid >> 5;
  const int bj = j0 + bcol;
  const int btb = bj / N_;
  const float* xb = X + (size_t)btb * CN_ + (bj - btb * N_);
  const int arow = tid >> 1;
  const int ac8 = (tid & 1) * 8;
  const float* wrow0 = W + (size_t)(co0 + arow) * C_ + ac8;

  // Prefetch tile 0 into registers.
  float4 pa0 = *(const float4*)(wrow0);
  float4 pa1 = *(const float4*)(wrow0 + 4);
  float4 pb0 = *(const float4*)(xb + (size_t)bk * N_);
  float4 pb1 = *(const float4*)(xb + (size_t)(bk + 8) * N_);

  float acc[8][8] = {};
  for (int c0 = 0; c0 < C_; c0 += 16) {
    __syncthreads();   // prev-iter readers done (no-op on first iter)
    As[ac8 + 0][arow] = pa0.x; As[ac8 + 1][arow] = pa0.y;
    As[ac8 + 2][arow] = pa0.z; As[ac8 + 3][arow] = pa0.w;
    As[ac8 + 4][arow] = pa1.x; As[ac8 + 5][arow] = pa1.y;
    As[ac8 + 6][arow] = pa1.z; As[ac8 + 7][arow] = pa1.w;
    *(float4*)&Bs[bk][bcol] = pb0;
    *(float4*)&Bs[bk + 8][bcol] = pb1;
    __syncthreads();
    if (c0 + 16 < C_) {  // prefetch next tile; latency hidden by compute below
      pa0 = *(const float4*)(wrow0 + c0 + 16);
      pa1 = *(const float4*)(wrow0 + c0 + 20);
      pb0 = *(const float4*)(xb + (size_t)(c0 + 16 + bk) * N_);
      pb1 = *(const float4*)(xb + (size_t)(c0 + 24 + bk) * N_);
    }
#pragma unroll
    for (int k = 0; k < 16; ++k) {
      float a[8], b[8];
      *(float4*)&a[0] = *(const float4*)&As[k][ty * 4];
      *(float4*)&a[4] = *(const float4*)&As[k][64 + ty * 4];
      *(float4*)&b[0] = *(const float4*)&Bs[k][tx * 4];
      *(float4*)&b[4] = *(const float4*)&Bs[k][64 + tx * 4];
#pragma unroll
      for (int i = 0; i < 8; ++i)
#pragma unroll
        for (int j = 0; j < 8; ++j)
          acc[i][j] = fmaf(a[i], b[j], acc[i][j]);
    }
  }
#pragma unroll
  for (int cg = 0; cg < 2; ++cg) {
    const int jj = j0 + cg * 64 + tx * 4;
    const int tb = jj / N_;
    float* pb = P + (size_t)(g * TB_ + tb) * CN_ + (jj - tb * N_);
#pragma unroll
    for (int rg = 0; rg < 2; ++rg) {
#pragma unroll
      for (int i = 0; i < 4; ++i) {
        const int r = rg * 4 + i;
        const int co = co0 + rg * 64 + ty * 4 + i;
        *(float4*)&pb[(size_t)co * N_] = make_float4(
            acc[r][cg * 4 + 0], acc[r][cg * 4 + 1],
            acc[r][cg * 4 + 2], acc[r][cg * 4 + 3]);
      }
    }
  }
}

// ---------------------------------------------------------------------------
// Multi-step LIF over t with folded BN (final conv only).
// ---------------------------------------------------------------------------
__global__ __launch_bounds__(256) void lif4(
    const float* __restrict__ In, float* __restrict__ Out,
    const float* __restrict__ s0, const float* __restrict__ b0, float vth)
{
  const long u = (long)blockIdx.x * 256 + threadIdx.x;
  if (u >= BCN4_) return;
  const long r = u;
  const int c = (int)((r / (N_ / 4)) % C_);
  const bool has_bn = (s0 != nullptr);
  const float sc = has_bn ? s0[c] : 1.0f;
  const float bi = has_bn ? b0[c] : 0.0f;
  const float4* In4 = (const float4*)In;
  float4* Out4 = (float4*)Out;
  float v[4] = {0.f, 0.f, 0.f, 0.f};
#pragma unroll
  for (int t = 0; t < T_; ++t) {
    const long idx = (long)t * BCN4_ + r;
    const float4 y4 = In4[idx];
    float y[4] = {y4.x, y4.y, y4.z, y4.w};
    float o[4];
#pragma unroll
    for (int e = 0; e < 4; ++e) {
      const float yb = has_bn ? __fadd_rn(__fmul_rn(y[e], sc), bi) : y[e];
      v[e] = __fadd_rn(v[e], __fmul_rn(__fsub_rn(yb, v[e]), 0.5f));
      const bool fire = (v[e] >= vth);
      o[e] = fire ? 1.0f : 0.0f;
      v[e] = fire ? 0.0f : v[e];
    }
    Out4[idx] = make_float4(o[0], o[1], o[2], o[3]);
  }
}

// ---------------------------------------------------------------------------
// k_mask: conv-LIF -> spike bitmasks, n-contiguous float4 reads.
// Wave-task = (g,h,b,j). Lane l (<49) reads float4 at n=4l for each t
// (4 independent 784-B dense streams). Spike for m sits at word m&3,
// bit m>>2 (permutation invariant for all popcounts; qT re-indexed).
// MSK layout: [(h*32+b)][g][t][j][w], 2304 u64 per (h,b).
// ---------------------------------------------------------------------------
__global__ __launch_bounds__(256) void k_mask(
    const float* __restrict__ P, u64* __restrict__ MSK,
    const float* __restrict__ sq, const float* __restrict__ bq,
    const float* __restrict__ sk, const float* __restrict__ bk,
    const float* __restrict__ sv, const float* __restrict__ bv)
{
  const int wave = threadIdx.x >> 6, lane = threadIdx.x & 63;
  const int task = blockIdx.x * 4 + wave;      // 0..36863
  const int j = task % D_;
  int r = task / D_;
  const int b = r & 31; r >>= 5;
  const int h = r & 7;  r >>= 3;
  const int g = r;                              // 0..2
  const int c = h * D_ + j;
  const float sc = (g == 0 ? sq : g == 1 ? sk : sv)[c];
  const float bi = (g == 0 ? bq : g == 1 ? bk : bv)[c];
  const bool act = (lane < 49);                 // 49*4 = 196 exactly
  const int nq = act ? lane * 4 : 192;
  const float* base = P + (size_t)g * TB_ * CN_ + (size_t)b * CN_
                        + (size_t)c * N_ + nq;
  float4 y[T_];
#pragma unroll
  for (int t = 0; t < T_; ++t)
    y[t] = *(const float4*)(base + (size_t)t * B_ * CN_);  // 4 indep streams

  u64* mb = MSK + ((size_t)(h * 32 + b) * 3 + g) * (T_ * D_ * 4) + j * 4;
  float v[4] = {0.f, 0.f, 0.f, 0.f};
#pragma unroll
  for (int t = 0; t < T_; ++t) {
    const float ya[4] = {y[t].x, y[t].y, y[t].z, y[t].w};
#pragma unroll
    for (int e = 0; e < 4; ++e) {
      const float yb = __fadd_rn(__fmul_rn(ya[e], sc), bi);
      v[e] = __fadd_rn(v[e], __fmul_rn(__fsub_rn(yb, v[e]), 0.5f));
      const bool fire = (v[e] >= 1.0f);
      if (fire) v[e] = 0.f;
      const u64 bl = __ballot(fire && act);     // word e, bit = lane = m>>2
      if (lane == 0) mb[(size_t)t * (D_ * 4) + e] = bl;
    }
  }
}

// ---------------------------------------------------------------------------
// k_attn: grid (h, b, dq). Each block loads masks, rebuilds qT + G
// bit-planes (redundant across dq, cheap), then Phase B for its d-quarter.
// ---------------------------------------------------------------------------
__global__ __launch_bounds__(256) void k_attn(
    const u64* __restrict__ MSK, float* __restrict__ O)
{
  const int h = blockIdx.x, b = blockIdx.y, dq = blockIdx.z;
  __shared__ u64 msk[3][T_][D_][4];   // 18432 B
  __shared__ u64 qT[T_][200];         // 6400 B
  __shared__ u64 Gp[T_][8][D_];       // 12288 B
  const int tid = threadIdx.x;
  const int wave = tid >> 6, lane = tid & 63;

  {
    const u64* ms = MSK + (size_t)(h * 32 + b) * 2304;
    u64* mf = &msk[0][0][0][0];
    for (int off = tid; off < 2304; off += 256) mf[off] = ms[off];
  }
  __syncthreads();

  // qT[t][n] = q bits over j (permuted mask: word n&3, bit n>>2)
  for (int u = tid; u < T_ * N_; u += 256) {
    const int t = u / N_, n = u - (u / N_) * N_;
    const int w = n & 3, s = n >> 2;
    u64 qr = 0ull;
#pragma unroll 8
    for (int j = 0; j < D_; ++j)
      qr |= ((msk[0][t][j][w] >> s) & 1ull) << j;
    qT[t][n] = qr;
  }
  // Gp[t][p][d]: bit-planes of G[j][d] = popcount_m(k_j & v_d), lanes=j
  for (int task = wave; task < T_ * D_; task += 4) {
    const int t = task / D_, d = task - (task / D_) * D_;
    const bool ja = (lane < D_);
    const int j = ja ? lane : (D_ - 1);
    const u64* kj = msk[1][t][j];
    const u64* vd = msk[2][t][d];
    const int gi = __popcll(kj[0] & vd[0]) + __popcll(kj[1] & vd[1]) +
                   __popcll(kj[2] & vd[2]) + __popcll(kj[3] & vd[3]);
#pragma unroll
    for (int p = 0; p < 8; ++p) {
      const u64 bl = __ballot(ja && ((gi >> p) & 1));
      if (lane == 0) Gp[t][p][d] = bl;
    }
  }
  __syncthreads();

  // Phase B for this block's d-quarter
  if (tid < N_) {
    const int n = tid;
    const int d0 = dq * 12;
    float vmem[12];
#pragma unroll
    for (int i = 0; i < 12; ++i) vmem[i] = 0.f;
    for (int t = 0; t < T_; ++t) {
      const u64 qr = qT[t][n];
      float* ob = O + ((size_t)(t * B_ + b) * C_ + h * D_ + d0) * N_ + n;
#pragma unroll
      for (int i = 0; i < 12; ++i) {
        int acc = 0;
#pragma unroll
        for (int p = 0; p < 8; ++p)
          acc += __popcll(qr & Gp[t][p][d0 + i]) << p;
        const float y = __int2float_rn(acc) * 0.125f;  // exact
        vmem[i] = __fadd_rn(vmem[i], __fmul_rn(__fsub_rn(y, vmem[i]), 0.5f));
        const bool fire = (vmem[i] >= 0.5f);
        ob[(size_t)i * N_] = fire ? 1.0f : 0.0f;
        if (fire) vmem[i] = 0.f;
      }
    }
  }
}

// ---------------------------------------------------------------------------
extern "C" void kernel_launch(void* const* d_in, const int* in_sizes, int n_in,
                              void* d_out, int out_size, void* d_ws, size_t ws_size,
                              hipStream_t stream) {
  const float* x  = (const float*)d_in[0];
  const float* wq = (const float*)d_in[1];
  const float* sq = (const float*)d_in[2];
  const float* bq = (const float*)d_in[3];
  const float* wk = (const float*)d_in[4];
  const float* sk = (const float*)d_in[5];
  const float* bk = (const float*)d_in[6];
  const float* wv = (const float*)d_in[7];
  const float* sv = (const float*)d_in[8];
  const float* bv = (const float*)d_in[9];
  const float* wp = (const float*)d_in[10];
  const float* sp = (const float*)d_in[11];
  const float* bp = (const float*)d_in[12];
  float* out = (float*)d_out;

  float* P = (float*)d_ws;              // 3*TBCN qkv preacts
  float* O = P + 3 * TBCN_;             // TBCN attn spikes
  u64* MSK = (u64*)(P + 4 * TBCN_);     // 256 * 2304 u64 = 4.7 MB
  float* P2 = P;                        // final conv preact reuses q region

  gemm_f32<<<dim3(196, 3, 3), 256, 0, stream>>>(x, wq, wk, wv, P);
  k_mask<<<dim3(9216), 256, 0, stream>>>(P, MSK, sq, bq, sk, bk, sv, bv);
  k_attn<<<dim3(NH_, B_, 4), 256, 0, stream>>>(MSK, O);
  gemm_f32<<<dim3(196, 3, 1), 256, 0, stream>>>(O, wp, wp, wp, P2);
  lif4<<<dim3((BCN4_ + 255) / 256), 256, 0, stream>>>(P2, out, sp, bp, 1.0f);
}